// Round 17
// baseline (128.997 us; speedup 1.0000x reference)
//
#include <hip/hip_runtime.h>
#include <math.h>

// Problem constants
#define E_     64     // embedding dim == wavefront size
#define ND_    40     // diseases per visit
#define NM_    30     // medications per visit
#define NSTEP_ 31     // NM+1 decode steps
#define VO_    133    // VM+2 output vocab
#define J3_    192    // 3*E (GRU gates)
#define NROW_  8192   // B*S
#define RPB_   8      // rows per block (M-tile 16, rows 8..15 zero)
#define SOS_   131    // VM
#define NC_    344    // sC stride (f32)

typedef __attribute__((ext_vector_type(8))) short short8;
typedef __attribute__((ext_vector_type(4))) float f32x4;

__device__ __forceinline__ float sigmoidf_(float x){ return 1.f/(1.f+__expf(-x)); }
__device__ __forceinline__ float tanhf_(float x){
  float ax = fabsf(x);
  float t = 1.f - 2.f/(__expf(2.f*ax)+1.f);   // stable, saturates to 1
  return copysignf(t, x);
}
__device__ __forceinline__ unsigned short f2bf(float f){
  union { float f; unsigned u; } x; x.f = f;
  unsigned r = (x.u + 0x7fffu + ((x.u >> 16) & 1u)) >> 16;  // RNE
  return (unsigned short)r;
}
__device__ __forceinline__ short8 pack8_(const float* __restrict__ s){
  short8 f;
  #pragma unroll
  for (int j=0;j<8;++j) f[j] = (short)f2bf(s[j]);
  return f;
}

// lgkm-only barrier: does NOT drain vmcnt, so in-flight global stores
// (output stream) are never waited on at step boundaries.
__device__ __forceinline__ void bar_lds(){
  asm volatile("s_waitcnt lgkmcnt(0)" ::: "memory");
  __builtin_amdgcn_s_barrier();
  asm volatile("" ::: "memory");
}

// ---------------------------------------------------------------------------
// Kernel A: P_med[v][j] = sum_e med_table[v][e] * W_ih[j][64+e]   (134x192)
// ---------------------------------------------------------------------------
__global__ __launch_bounds__(256) void k_pmed(const float* __restrict__ mt,
    const float* __restrict__ wih, float* __restrict__ pmed){
  int o = blockIdx.x*256 + threadIdx.x;
  if (o >= 134*J3_) return;
  int v = o / J3_, j = o - v*J3_;
  const float* mr = mt + v*E_;
  const float* wr = wih + j*128 + E_;
  float a = 0.f;
  #pragma unroll
  for (int k=0;k<E_;k++) a = fmaf(mr[k], wr[k], a);
  pmed[o] = a;
}

// ---------------------------------------------------------------------------
// Fused cooperative decoder — round-10 schedule at GRID-DOUBLED occupancy.
// r10's occupancy limiter was the grid (512 blocks = 2 blocks/CU = 16
// waves/CU at VGPR=60), not registers. This build: RPB=8 -> 1024 blocks x
// 512 threads = 4 blocks/CU resident (32 waves/CU, 4 barrier domains),
// launch_bounds(512,4) UNCHANGED so codegen stays at its natural ~60 VGPR
// (no cap-induced spill — the r4/r5/r11/r15 failure mode excluded).
// Per step: combined GEMM h_t(8x64 in M-tile 16, rows 8..15 zero) x
// [W_hh^T|wo^T](64x336), 21 n-tiles {w,w+8,w+16(w<5)} as register B-frags;
// pointwise GRU 1 dim/thread (64 thr/row); max-free log_softmax full-wave
// (3 cols/lane). lgkm-only barriers; pmed(t+1) issued before out stores.
// ---------------------------------------------------------------------------
__global__ __launch_bounds__(512,4) void k_main(
    const int* __restrict__ dis, const float* __restrict__ dmask,
    const float* __restrict__ dt, const float* __restrict__ aw,
    const int* __restrict__ meds,
    const float* __restrict__ whh, const float* __restrict__ bhh,
    const float* __restrict__ wih, const float* __restrict__ bih,
    const float* __restrict__ wo, const float* __restrict__ wob,
    const float* __restrict__ mt, const float* __restrict__ pmed,
    float* __restrict__ out)
{
  __shared__ __align__(16) unsigned short hA[16*E_];    // 2KB swizzled bf16 h
  __shared__ __align__(16) float sC[16*NC_];            // 22KB GEMM out
  __shared__ int sLM[RPB_*32];                          // 1KB last-med idx

  const int tid = threadIdx.x;
  const int w = tid >> 6, l = tid & 63;
  const int l15 = l & 15, l4 = l >> 4;
  const int rowbase = blockIdx.x * RPB_;
  const int grow = rowbase + w;             // this wave's row (1 row/wave)
  const int swz = l ^ ((w&7)<<3);           // hA element swizzle for row w

  // ---- last-med indices (8 rows x 31 steps) ----
  {
    int rr = tid >> 5, t = tid & 31;
    if (rr < RPB_ && t < NSTEP_)
      sLM[rr*32 + t] = (t==0) ? SOS_ : meds[(size_t)(rowbase+rr)*NM_ + (t-1)];
  }
  // ---- zero hA rows 8..15 (M-tile 16, only 8 real rows) ----
  for (int i = tid; i < 8*E_; i += 512) hA[8*E_ + i] = 0;

  // ======== prologue: attention ctx for row w (h-independent) ========
  float wd = aw[E_ + l];
  {
    const int*   drow = dis   + (size_t)grow*ND_;
    const float* mrow = dmask + (size_t)grow*ND_;
    float dreg[ND_], sc[ND_];
    float mx = -INFINITY;
    #pragma unroll
    for (int n = 0; n < ND_; ++n){
      float d = dt[(size_t)drow[n]*E_ + l];
      dreg[n] = d;
      float p = d * wd;
      #pragma unroll
      for (int m=1;m<64;m<<=1) p += __shfl_xor(p, m);
      sc[n] = p + mrow[n];
      mx = fmaxf(mx, sc[n]);
    }
    float ss = 0.f, ctx = 0.f;
    #pragma unroll
    for (int n = 0; n < ND_; ++n){
      float e = __expf(sc[n]-mx);
      ss += e;
      ctx = fmaf(e, dreg[n], ctx);
    }
    ctx /= ss;
    hA[w*E_ + swz] = f2bf(ctx);             // swizzled A-tile row w
  }
  __syncthreads();

  // ======== prologue: gi = ctx @ W_ih_left^T (cooperative MFMA) ========
  {
    short8 A00 = *(const short8*)&hA[l15*E_ + ((l4*8     ) ^ ((l15&7)<<3))];
    short8 A01 = *(const short8*)&hA[l15*E_ + ((32 + l4*8) ^ ((l15&7)<<3))];
    #pragma unroll
    for (int jj = 0; jj < 2; ++jj){
      int n = w + 8*jj;
      if (n < 12){                              // 12 tiles cover 192 cols
        int c = n*16 + l15;
        short8 B0 = pack8_(wih + (size_t)c*128 + l4*8);
        short8 B1 = pack8_(wih + (size_t)c*128 + 32 + l4*8);
        f32x4 cc = {0.f,0.f,0.f,0.f};
        cc = __builtin_amdgcn_mfma_f32_16x16x32_bf16(A00, B0, cc, 0,0,0);
        cc = __builtin_amdgcn_mfma_f32_16x16x32_bf16(A01, B1, cc, 0,0,0);
        #pragma unroll
        for (int i=0;i<4;i++) sC[(l4*4+i)*NC_ + c] = cc[i];
      }
    }
  }
  __syncthreads();
  // per-thread gi (row w, dim l), fold biases
  float gia = sC[w*NC_ + l]       + bih[l]     + bhh[l];
  float giz = sC[w*NC_ + l + 64]  + bih[l+64]  + bhh[l+64];
  float gin = sC[w*NC_ + l + 128] + bih[l+128];
  float bhn = bhh[l + 128];
  // wob per softmax col (idx = l + 64k)
  float wbv[3];
  #pragma unroll
  for (int k = 0; k < 3; ++k){
    int idx = l + 64*k;
    wbv[k] = (idx < VO_) ? wob[idx] : -1e30f;
  }

  // ======== combined-weight register B-fragments: wave w tiles {w,w+8,w+16}
  short8 B0[3], B1[3];
  const int ntile = (w < 5) ? 3 : 2;
  #pragma unroll
  for (int j = 0; j < 3; ++j){
    short8 z = {0,0,0,0,0,0,0,0};
    B0[j] = z; B1[j] = z;
    if (j < ntile){
      int c = (w + 8*j)*16 + l15;
      #pragma unroll
      for (int ks = 0; ks < 2; ++ks){
        int k0 = ks*32 + l4*8;
        float v[8];
        if (c < J3_){
          const float* s = whh + (size_t)c*E_ + k0;
          #pragma unroll
          for (int jj=0;jj<8;jj++) v[jj] = s[jj];
        } else if (c < 192+VO_){
          const float* s = wo + (size_t)(c-192)*E_ + k0;
          #pragma unroll
          for (int jj=0;jj<8;jj++) v[jj] = s[jj];
        } else {
          #pragma unroll
          for (int jj=0;jj<8;jj++) v[jj] = 0.f;
        }
        short8 f;
        #pragma unroll
        for (int jj=0;jj<8;jj++) f[jj] = (short)f2bf(v[jj]);
        if (ks==0) B0[j] = f; else B1[j] = f;
      }
    }
  }

  // ======== h0 = med_table[SOS]; thread holds (row w, dim l) ========
  float hr = mt[SOS_*E_ + l];
  hA[w*E_ + swz] = f2bf(hr);
  __syncthreads();

  // ---- prefetch pmed for t=0 ----
  int lm = sLM[w*32];
  float pr = pmed[(size_t)lm*J3_ + l];
  float pz = pmed[(size_t)lm*J3_ + l + 64];
  float pn = pmed[(size_t)lm*J3_ + l + 128];

  // ======== main loop: 32 iterations (gh at t, logits for t-1) ========
  for (int t = 0; t <= NSTEP_; ++t){
    short8 A00 = *(const short8*)&hA[l15*E_ + ((l4*8     ) ^ ((l15&7)<<3))];
    short8 A01 = *(const short8*)&hA[l15*E_ + ((32 + l4*8) ^ ((l15&7)<<3))];
    #pragma unroll
    for (int j = 0; j < 3; ++j){
      if (j < ntile){
        f32x4 cc = {0.f,0.f,0.f,0.f};
        cc = __builtin_amdgcn_mfma_f32_16x16x32_bf16(A00, B0[j], cc, 0,0,0);
        cc = __builtin_amdgcn_mfma_f32_16x16x32_bf16(A01, B1[j], cc, 0,0,0);
        int c = (w + 8*j)*16 + l15;
        #pragma unroll
        for (int i=0;i<4;i++) sC[(l4*4+i)*NC_ + c] = cc[i];
      }
    }
    bar_lds();

    // ---- prefetch pmed for t+1 (loads issued BEFORE this step's stores) --
    float npr=0.f, npz=0.f, npn=0.f;
    if (t+1 < NSTEP_){
      int lmn = sLM[w*32 + t + 1];
      npr = pmed[(size_t)lmn*J3_ + l];
      npz = pmed[(size_t)lmn*J3_ + l + 64];
      npn = pmed[(size_t)lmn*J3_ + l + 128];
    }

    if (t < NSTEP_){
      // ---- pointwise GRU: dim l of row w ----
      float ghr = sC[w*NC_ + l];
      float ghz = sC[w*NC_ + l + 64];
      float ghn = sC[w*NC_ + l + 128];
      float rg = sigmoidf_(gia + pr + ghr);
      float zg = sigmoidf_(giz + pz + ghz);
      float ng = tanhf_(gin + pn + rg*(ghn + bhn));
      hr = (1.f - zg)*ng + zg*hr;
      hA[w*E_ + swz] = f2bf(hr);
    }

    if (t >= 1){
      // ---- max-free log_softmax for step t-1 (logits = sC cols 192..324) -
      float lv[3]; float s = 0.f;
      #pragma unroll
      for (int k = 0; k < 3; ++k){
        int idx = l + 64*k;
        lv[k] = (idx < VO_) ? (sC[w*NC_ + 192 + idx] + wbv[k]) : -1e30f;
        s += __expf(lv[k]);
      }
      #pragma unroll
      for (int mm=1; mm<64; mm<<=1) s += __shfl_xor(s, mm);  // full wave
      float lg = __logf(s);
      size_t ob = ((size_t)grow*NSTEP_ + (t-1))*VO_;
      #pragma unroll
      for (int k = 0; k < 3; ++k){
        int idx = l + 64*k;
        if (idx < VO_) out[ob + idx] = lv[k] - lg;
      }
    }
    bar_lds();

    pr = npr; pz = npz; pn = npn;
  }
}

extern "C" void kernel_launch(void* const* d_in, const int* in_sizes, int n_in,
                              void* d_out, int out_size, void* d_ws, size_t ws_size,
                              hipStream_t stream){
  const int*   dis  = (const int*)  d_in[0];
  const int*   meds = (const int*)  d_in[2];
  const float* dmask= (const float*)d_in[3];
  const float* dt   = (const float*)d_in[6];
  const float* mt   = (const float*)d_in[7];
  const float* aw   = (const float*)d_in[8];
  const float* wih  = (const float*)d_in[10];
  const float* whh  = (const float*)d_in[11];
  const float* bih  = (const float*)d_in[12];
  const float* bhh  = (const float*)d_in[13];
  const float* wo   = (const float*)d_in[14];
  const float* wob  = (const float*)d_in[15];
  float* outp = (float*)d_out;
  float* pmed = (float*)d_ws;                     // 134*192 f32

  k_pmed<<<(134*J3_+255)/256, 256, 0, stream>>>(mt, wih, pmed);
  k_main<<<NROW_/RPB_, 512, 0, stream>>>(dis, dmask, dt, aw, meds,
                                         whh, bhh, wih, bih, wo, wob,
                                         mt, pmed, outp);
}

// Round 18
// 98.326 us; speedup vs baseline: 1.3119x; 1.3119x over previous
//
#include <hip/hip_runtime.h>
#include <math.h>

// Problem constants
#define E_     64     // embedding dim == wavefront size
#define ND_    40     // diseases per visit
#define NM_    30     // medications per visit
#define NSTEP_ 31     // NM+1 decode steps
#define VO_    133    // VM+2 output vocab
#define J3_    192    // 3*E (GRU gates)
#define NROW_  8192   // B*S
#define RPB_   16     // rows per block (= M-tile, all real)
#define SOS_   131    // VM
#define NC_    344    // sC stride (f32): 336 used cols + pad

typedef __attribute__((ext_vector_type(8))) short short8;
typedef __attribute__((ext_vector_type(4))) float f32x4;

__device__ __forceinline__ float sigmoidf_(float x){ return 1.f/(1.f+__expf(-x)); }
__device__ __forceinline__ float tanhf_(float x){
  float ax = fabsf(x);
  float t = 1.f - 2.f/(__expf(2.f*ax)+1.f);   // stable, saturates to 1
  return copysignf(t, x);
}
__device__ __forceinline__ unsigned short f2bf(float f){
  union { float f; unsigned u; } x; x.f = f;
  unsigned r = (x.u + 0x7fffu + ((x.u >> 16) & 1u)) >> 16;  // RNE
  return (unsigned short)r;
}
__device__ __forceinline__ short8 pack8_(const float* __restrict__ s){
  short8 f;
  #pragma unroll
  for (int j=0;j<8;++j) f[j] = (short)f2bf(s[j]);
  return f;
}

// lgkm-only barrier: does NOT drain vmcnt, so in-flight global stores
// (output stream) are never waited on at step boundaries.
__device__ __forceinline__ void bar_lds(){
  asm volatile("s_waitcnt lgkmcnt(0)" ::: "memory");
  __builtin_amdgcn_s_barrier();
  asm volatile("" ::: "memory");
}

// ---------------------------------------------------------------------------
// Kernel A: P_med[v][j] = sum_e med_table[v][e] * W_ih[j][64+e]   (134x192)
// ---------------------------------------------------------------------------
__global__ __launch_bounds__(256) void k_pmed(const float* __restrict__ mt,
    const float* __restrict__ wih, float* __restrict__ pmed){
  int o = blockIdx.x*256 + threadIdx.x;
  if (o >= 134*J3_) return;
  int v = o / J3_, j = o - v*J3_;
  const float* mr = mt + v*E_;
  const float* wr = wih + j*128 + E_;
  float a = 0.f;
  #pragma unroll
  for (int k=0;k<E_;k++) a = fmaf(mr[k], wr[k], a);
  pmed[o] = a;
}

// ---------------------------------------------------------------------------
// Fused cooperative decoder (rounds 10/16 configuration — session best,
// 97.9/98.3 us, reproduced). 512 blocks x 512 threads (8 waves), 16 rows/
// block = full M-tile (no wasted MFMA rows), 2 blocks/CU resident, VGPR=60.
// Per step: combined GEMM h_t(16x64) x [W_hh^T|wo^T](64x336) — 21 n-tiles
// split {w, w+8, w+16(w<5)} across 8 waves, B as register fragments;
// pointwise GRU 2 dims/thread; logits(t-1) softmax 32-wide (max-free:
// logits provably bounded, exp cannot overflow fp32).
// lgkm-only barriers; pmed loads for t+1 issued BEFORE step-t out stores.
// Floor evidence: occupancy up (r17 clean, r4/5/11 capped), barriers down
// (r6/7/14/15), pipelining (r13), phase-split (r6/7), specialization+
// setprio (r14/15), conflict-fix (r13) — ALL land at or above this time.
// ~3.1us/step = dependent-chain latency equilibrium at 32 rows/CU.
// ---------------------------------------------------------------------------
__global__ __launch_bounds__(512,4) void k_main(
    const int* __restrict__ dis, const float* __restrict__ dmask,
    const float* __restrict__ dt, const float* __restrict__ aw,
    const int* __restrict__ meds,
    const float* __restrict__ whh, const float* __restrict__ bhh,
    const float* __restrict__ wih, const float* __restrict__ bih,
    const float* __restrict__ wo, const float* __restrict__ wob,
    const float* __restrict__ mt, const float* __restrict__ pmed,
    float* __restrict__ out)
{
  __shared__ __align__(16) unsigned short hA[RPB_*E_];  // 2KB swizzled bf16 h
  __shared__ __align__(16) float sC[RPB_*NC_];          // 22KB GEMM out
  __shared__ int sLM[RPB_*32];                          // 2KB last-med idx

  const int tid = threadIdx.x;
  const int w = tid >> 6, l = tid & 63;
  const int l15 = l & 15, l4 = l >> 4;
  const int row = tid >> 5;                 // pointwise row (0..15)
  const int d0  = (tid & 31) * 2;           // pointwise dim pair
  const int rowbase = blockIdx.x * RPB_;
  const int grow = rowbase + row;

  // ---- last-med indices ----
  {
    int rr = tid >> 5, t = tid & 31;
    if (t < NSTEP_)
      sLM[rr*32 + t] = (t==0) ? SOS_ : meds[(size_t)(rowbase+rr)*NM_ + (t-1)];
  }

  // ======== prologue: attention ctx for rows 2w, 2w+1 (h-independent) ====
  float wd = aw[E_ + l];
  #pragma unroll 1
  for (int r2 = 0; r2 < 2; ++r2){
    int rr = 2*w + r2;
    const int*   drow = dis   + (size_t)(rowbase+rr)*ND_;
    const float* mrow = dmask + (size_t)(rowbase+rr)*ND_;
    float dreg[ND_], sc[ND_];
    float mx = -INFINITY;
    #pragma unroll
    for (int n = 0; n < ND_; ++n){
      float d = dt[(size_t)drow[n]*E_ + l];
      dreg[n] = d;
      float p = d * wd;
      #pragma unroll
      for (int m=1;m<64;m<<=1) p += __shfl_xor(p, m);
      sc[n] = p + mrow[n];
      mx = fmaxf(mx, sc[n]);
    }
    float ss = 0.f, ctx = 0.f;
    #pragma unroll
    for (int n = 0; n < ND_; ++n){
      float e = __expf(sc[n]-mx);
      ss += e;
      ctx = fmaf(e, dreg[n], ctx);
    }
    ctx /= ss;
    hA[rr*E_ + (l ^ ((rr&7)<<3))] = f2bf(ctx);   // swizzled A-tile row
  }
  __syncthreads();

  // ======== prologue: gi = ctx @ W_ih_left^T (cooperative MFMA) ========
  {
    short8 A00 = *(const short8*)&hA[l15*E_ + ((l4*8     ) ^ ((l15&7)<<3))];
    short8 A01 = *(const short8*)&hA[l15*E_ + ((32 + l4*8) ^ ((l15&7)<<3))];
    #pragma unroll
    for (int jj = 0; jj < 2; ++jj){
      int n = w + 8*jj;
      if (n < 12){                              // 12 tiles cover 192 cols
        int c = n*16 + l15;
        short8 B0 = pack8_(wih + (size_t)c*128 + l4*8);
        short8 B1 = pack8_(wih + (size_t)c*128 + 32 + l4*8);
        f32x4 cc = {0.f,0.f,0.f,0.f};
        cc = __builtin_amdgcn_mfma_f32_16x16x32_bf16(A00, B0, cc, 0,0,0);
        cc = __builtin_amdgcn_mfma_f32_16x16x32_bf16(A01, B1, cc, 0,0,0);
        #pragma unroll
        for (int i=0;i<4;i++) sC[(l4*4+i)*NC_ + c] = cc[i];
      }
    }
  }
  __syncthreads();
  // per-thread gi (row, dims d0..d0+1), fold biases
  float2 gir = *(const float2*)&sC[row*NC_ + d0];
  float2 giz = *(const float2*)&sC[row*NC_ + d0 + 64];
  float2 gin = *(const float2*)&sC[row*NC_ + d0 + 128];
  {
    float2 a = *(const float2*)&bih[d0],      b = *(const float2*)&bhh[d0];
    float2 c = *(const float2*)&bih[d0+64],   d = *(const float2*)&bhh[d0+64];
    float2 e = *(const float2*)&bih[d0+128];
    gir.x += a.x + b.x; gir.y += a.y + b.y;
    giz.x += c.x + d.x; giz.y += c.y + d.y;
    gin.x += e.x;       gin.y += e.y;
  }
  float2 bhn = *(const float2*)&bhh[d0 + 128];
  // wob per softmax col (idx = (tid&31) + 32k)
  float wbv[5];
  #pragma unroll
  for (int k = 0; k < 5; ++k){
    int idx = (tid&31) + 32*k;
    wbv[k] = (idx < VO_) ? wob[idx] : -1e30f;
  }

  // ======== combined-weight register B-fragments: wave w tiles {w,w+8,w+16}
  short8 B0[3], B1[3];
  const int ntile = (w < 5) ? 3 : 2;
  #pragma unroll
  for (int j = 0; j < 3; ++j){
    short8 z = {0,0,0,0,0,0,0,0};
    B0[j] = z; B1[j] = z;
    if (j < ntile){
      int c = (w + 8*j)*16 + l15;
      #pragma unroll
      for (int ks = 0; ks < 2; ++ks){
        int k0 = ks*32 + l4*8;
        float v[8];
        if (c < J3_){
          const float* s = whh + (size_t)c*E_ + k0;
          #pragma unroll
          for (int jj=0;jj<8;jj++) v[jj] = s[jj];
        } else if (c < 192+VO_){
          const float* s = wo + (size_t)(c-192)*E_ + k0;
          #pragma unroll
          for (int jj=0;jj<8;jj++) v[jj] = s[jj];
        } else {
          #pragma unroll
          for (int jj=0;jj<8;jj++) v[jj] = 0.f;
        }
        short8 f;
        #pragma unroll
        for (int jj=0;jj<8;jj++) f[jj] = (short)f2bf(v[jj]);
        if (ks==0) B0[j] = f; else B1[j] = f;
      }
    }
  }

  // ======== h0 = med_table[SOS]; thread holds (row, dims d0..d0+1) ========
  float2 hv2 = *(const float2*)&mt[SOS_*E_ + d0];
  {
    unsigned hv = (unsigned)f2bf(hv2.x) | ((unsigned)f2bf(hv2.y)<<16);
    *(unsigned*)&hA[row*E_ + (d0 ^ ((row&7)<<3))] = hv;
  }
  __syncthreads();

  // ---- prefetch pmed for t=0 ----
  int lm = sLM[row*32];
  float2 pr = *(const float2*)&pmed[(size_t)lm*J3_ + d0];
  float2 pz = *(const float2*)&pmed[(size_t)lm*J3_ + d0 + 64];
  float2 pn = *(const float2*)&pmed[(size_t)lm*J3_ + d0 + 128];

  // ======== main loop: 32 iterations (gh at t, logits for t-1) ========
  for (int t = 0; t <= NSTEP_; ++t){
    short8 A00 = *(const short8*)&hA[l15*E_ + ((l4*8     ) ^ ((l15&7)<<3))];
    short8 A01 = *(const short8*)&hA[l15*E_ + ((32 + l4*8) ^ ((l15&7)<<3))];
    #pragma unroll
    for (int j = 0; j < 3; ++j){
      if (j < ntile){
        f32x4 cc = {0.f,0.f,0.f,0.f};
        cc = __builtin_amdgcn_mfma_f32_16x16x32_bf16(A00, B0[j], cc, 0,0,0);
        cc = __builtin_amdgcn_mfma_f32_16x16x32_bf16(A01, B1[j], cc, 0,0,0);
        int c = (w + 8*j)*16 + l15;
        #pragma unroll
        for (int i=0;i<4;i++) sC[(l4*4+i)*NC_ + c] = cc[i];
      }
    }
    bar_lds();

    // ---- prefetch pmed for t+1 (LOADS issued BEFORE this step's stores) --
    int lmn = 0; float2 npr, npz, npn;
    if (t+1 < NSTEP_){
      lmn = sLM[row*32 + t + 1];
      npr = *(const float2*)&pmed[(size_t)lmn*J3_ + d0];
      npz = *(const float2*)&pmed[(size_t)lmn*J3_ + d0 + 64];
      npn = *(const float2*)&pmed[(size_t)lmn*J3_ + d0 + 128];
    }

    if (t < NSTEP_){
      // ---- pointwise GRU: 2 dims of row `row` ----
      float2 ghr = *(const float2*)&sC[row*NC_ + d0];
      float2 ghz = *(const float2*)&sC[row*NC_ + d0 + 64];
      float2 ghn = *(const float2*)&sC[row*NC_ + d0 + 128];
      {
        float rg = sigmoidf_(gir.x + pr.x + ghr.x);
        float zg = sigmoidf_(giz.x + pz.x + ghz.x);
        float ng = tanhf_(gin.x + pn.x + rg*(ghn.x + bhn.x));
        hv2.x = (1.f - zg)*ng + zg*hv2.x;
      }
      {
        float rg = sigmoidf_(gir.y + pr.y + ghr.y);
        float zg = sigmoidf_(giz.y + pz.y + ghz.y);
        float ng = tanhf_(gin.y + pn.y + rg*(ghn.y + bhn.y));
        hv2.y = (1.f - zg)*ng + zg*hv2.y;
      }
      unsigned hv = (unsigned)f2bf(hv2.x) | ((unsigned)f2bf(hv2.y)<<16);
      *(unsigned*)&hA[row*E_ + (d0 ^ ((row&7)<<3))] = hv;
    }

    if (t >= 1){
      // ---- max-free log_softmax for step t-1 (logits = sC cols 192..324) -
      float lv[5]; float s = 0.f;
      #pragma unroll
      for (int k = 0; k < 5; ++k){
        int idx = (tid&31) + 32*k;
        lv[k] = (idx < VO_) ? (sC[row*NC_ + 192 + idx] + wbv[k]) : -1e30f;
        s += __expf(lv[k]);
      }
      #pragma unroll
      for (int mm=1; mm<32; mm<<=1) s += __shfl_xor(s, mm);  // 32-wide (row)
      float lg = __logf(s);
      size_t ob = ((size_t)grow*NSTEP_ + (t-1))*VO_;
      #pragma unroll
      for (int k = 0; k < 5; ++k){
        int idx = (tid&31) + 32*k;
        if (idx < VO_) out[ob + idx] = lv[k] - lg;
      }
    }
    bar_lds();

    if (t+1 < NSTEP_){ pr = npr; pz = npz; pn = npn; }
  }
}

extern "C" void kernel_launch(void* const* d_in, const int* in_sizes, int n_in,
                              void* d_out, int out_size, void* d_ws, size_t ws_size,
                              hipStream_t stream){
  const int*   dis  = (const int*)  d_in[0];
  const int*   meds = (const int*)  d_in[2];
  const float* dmask= (const float*)d_in[3];
  const float* dt   = (const float*)d_in[6];
  const float* mt   = (const float*)d_in[7];
  const float* aw   = (const float*)d_in[8];
  const float* wih  = (const float*)d_in[10];
  const float* whh  = (const float*)d_in[11];
  const float* bih  = (const float*)d_in[12];
  const float* bhh  = (const float*)d_in[13];
  const float* wo   = (const float*)d_in[14];
  const float* wob  = (const float*)d_in[15];
  float* outp = (float*)d_out;
  float* pmed = (float*)d_ws;                     // 134*192 f32

  k_pmed<<<(134*J3_+255)/256, 256, 0, stream>>>(mt, wih, pmed);
  k_main<<<NROW_/RPB_, 512, 0, stream>>>(dis, dmask, dt, aw, meds,
                                         whh, bhh, wih, bih, wo, wob,
                                         mt, pmed, outp);
}